// Round 2
// baseline (155.498 us; speedup 1.0000x reference)
//
#include <hip/hip_runtime.h>
#include <hip/hip_bf16.h>
#include <math.h>

// B=8, N=32, S=512, H=768, K=3, C=128, L=64, W=16
#define NEG_INF (-1e30f)

typedef _Float16 half8 __attribute__((ext_vector_type(8)));
typedef _Float16 half4 __attribute__((ext_vector_type(4)));
typedef float f32x4 __attribute__((ext_vector_type(4)));
typedef float f32x16 __attribute__((ext_vector_type(16)));

__device__ __forceinline__ void load_lds16(const void* g, void* l) {
  __builtin_amdgcn_global_load_lds((const __attribute__((address_space(1))) void*)g,
                                   (__attribute__((address_space(3))) void*)l, 16, 0, 0);
}

// ---------------------------------------------------------------------------
// Kernel 1 (prep): 2-plane split (K=1536):
//   A2 [4096 x 1536] f16 = [A_hi | A_lo*2^6]
//   Bt [1152 x 1536] f16 (j-major) = [B_hi | B_lo*2^6]
//   fcT[i][c] fp32
// ---------------------------------------------------------------------------
__global__ __launch_bounds__(256) void prep(
    const float* __restrict__ tokens, const float* __restrict__ span_w,
    const float* __restrict__ prefix_w, const float* __restrict__ suffix_w,
    const float* __restrict__ fc_w, _Float16* __restrict__ A2,
    _Float16* __restrict__ Bt, float* __restrict__ fcT) {
  int bid = blockIdx.x;
  int t = threadIdx.x;
  if (bid < 3072) {  // A2
    int g4 = (bid * 256 + t) * 4;
    int m = g4 / 768, h = g4 % 768;
    float4 x = *(const float4*)(tokens + g4);
    float xs[4] = {x.x, x.y, x.z, x.w};
    half4 hi, lo;
#pragma unroll
    for (int i = 0; i < 4; ++i) {
      _Float16 h_ = (_Float16)xs[i];
      hi[i] = h_;
      lo[i] = (_Float16)((xs[i] - (float)h_) * 64.0f);
    }
    size_t base = (size_t)m * 1536 + h;
    *(half4*)(A2 + base) = hi;
    *(half4*)(A2 + base + 768) = lo;
  } else if (bid < 3216) {  // Bt
    int g = (bid - 3072) * 256 + t;  // over 3*128*96 = 36864
    int ws = g / 12288;
    int r = g % 12288;
    int c = r / 96, h = (r % 96) * 8;
    const float* wsrc = (ws == 0) ? prefix_w : (ws == 1) ? span_w : suffix_w;
    const float* src = wsrc + (size_t)(c * 768 + h) * 3;
    float wv[24];
#pragma unroll
    for (int i = 0; i < 6; ++i) *(float4*)&wv[i * 4] = *(const float4*)(src + i * 4);
#pragma unroll
    for (int tap = 0; tap < 3; ++tap) {
      half8 hi, lo;
#pragma unroll
      for (int i = 0; i < 8; ++i) {
        float x = wv[i * 3 + tap];
        _Float16 h_ = (_Float16)x;
        hi[i] = h_;
        lo[i] = (_Float16)((x - (float)h_) * 64.0f);
      }
      size_t jb = (size_t)(ws * 384 + tap * 128 + c) * 1536 + h;
      *(half8*)(Bt + jb) = hi;
      *(half8*)(Bt + jb + 768) = lo;
    }
  } else {  // fcT
    int g = (bid - 3216) * 256 + t;
    int i = g >> 6, c = g & 63;
    fcT[g] = fc_w[c * 384 + i];
  }
}

// ---------------------------------------------------------------------------
// Kernel 2: MFMA GEMM with mfma_f32_32x32x16_f16.
//   Ct[j][m] = aa + 2^-6 * ab;  per k16: aa += A0*B0; ab += A1*B0 + A0*B1.
//   M=4096, N=1152, Kplane=768. BM=128, BN=64, BK=32, 512 thr (8 waves),
//   wave-tile 32x32 (round-0 layout, known good). Grid (32,18)=576.
//   NEW (this round, T4): 3-buffer depth-2 prefetch with RAW barriers +
//   counted vmcnt. Iter t: issue stage(t+2) -> compute(t) -> lgkmcnt(0)
//   (reads consumed; overwrite-safe) -> vmcnt(3) (only t+1's 3 loads must
//   land; t+2's stay in flight ACROSS the barrier) -> s_barrier. Removes the
//   per-iter vmcnt(0) drain (~200-900cy L2/HBM latency) that __syncthreads
//   forced (r1 counters: MfmaUtil 17%, VALUBusy 8%, occ 18%, HBM 11% ->
//   latency-bound, nothing saturated). LDS 3x24KB=72KB -> 2 blocks/CU.
//   LDS row = 64 halfs = [p0 k0..31 | p1 k0..31], 16B chunks XOR-swizzled by
//   row&7.
// ---------------------------------------------------------------------------
__global__ __launch_bounds__(512) void gemm_f16(const _Float16* __restrict__ A2,
                                                const _Float16* __restrict__ Bt,
                                                float* __restrict__ Ct) {
  __shared__ _Float16 As[3][128 * 64];  // 3 x 16 KB
  __shared__ _Float16 Bs[3][64 * 64];   // 3 x 8 KB
  const int bm = blockIdx.x * 128;
  const int bj = blockIdx.y * 64;
  const int tid = threadIdx.x;
  const int w = tid >> 6;
  const int lane = tid & 63;
  // staging: each glds covers 8 rows x 8 chunks (1024 B); lane -> (lrow, cphys)
  const int lrow = lane >> 3;
  const int cphys = lane & 7;
  const int clog = cphys ^ (lrow & 7);
  const int srcoff = (clog >> 2) * 768 + (clog & 3) * 8;  // plane + k-sub
  const _Float16* gA0 = A2 + (size_t)(bm + w * 16 + lrow) * 1536 + srcoff;
  const _Float16* gA1 = A2 + (size_t)(bm + w * 16 + 8 + lrow) * 1536 + srcoff;
  const _Float16* gB0 = Bt + (size_t)(bj + w * 8 + lrow) * 1536 + srcoff;
  // fragment read constants (32x32x16: m/n = lane&31, k = (lane>>5)*8 + j)
  const int m0w = (w & 3) * 32;
  const int n0w = (w >> 2) * 32;
  const int arow = m0w + (lane & 31);
  const int brow = n0w + (lane & 31);
  const int hi32 = lane >> 5;
  const int sw = lane & 7;  // arow&7 == brow&7 == lane&7
#define CO(p, ks) (((((p) * 4 + (ks) * 2 + hi32)) ^ sw) * 8)
#define STAGE(sb, t)                             \
  do {                                           \
    const int kp_ = (t) * 32;                    \
    load_lds16(gA0 + kp_, &As[(sb)][w * 1024]);  \
    load_lds16(gA1 + kp_, &As[(sb)][w * 1024 + 512]); \
    load_lds16(gB0 + kp_, &Bs[(sb)][w * 512]);   \
  } while (0)
  f32x16 aa, ab;
#pragma unroll
  for (int q = 0; q < 16; ++q) {
    aa[q] = 0.f;
    ab[q] = 0.f;
  }
  // prologue: stage iters 0,1 (depth-2); only require buf0 before iter 0.
  STAGE(0, 0);
  STAGE(1, 1);
  asm volatile("s_waitcnt vmcnt(3)" ::: "memory");
  __builtin_amdgcn_s_barrier();

  int cur = 0, sbuf = 2;
  for (int t = 0; t < 24; ++t) {
    if (t + 2 < 24) STAGE(sbuf, t + 2);  // in flight: (t+1)'s 3 + these 3
#pragma unroll
    for (int ks = 0; ks < 2; ++ks) {
      half8 a0 = *(const half8*)&As[cur][arow * 64 + CO(0, ks)];
      half8 a1 = *(const half8*)&As[cur][arow * 64 + CO(1, ks)];
      half8 b0 = *(const half8*)&Bs[cur][brow * 64 + CO(0, ks)];
      half8 b1 = *(const half8*)&Bs[cur][brow * 64 + CO(1, ks)];
      aa = __builtin_amdgcn_mfma_f32_32x32x16_f16(a0, b0, aa, 0, 0, 0);
      ab = __builtin_amdgcn_mfma_f32_32x32x16_f16(a1, b0, ab, 0, 0, 0);
      ab = __builtin_amdgcn_mfma_f32_32x32x16_f16(a0, b1, ab, 0, 0, 0);
    }
    if (t < 23) {
      // reads of buf[cur] consumed before anyone overwrites it next iter
      asm volatile("s_waitcnt lgkmcnt(0)" ::: "memory");
      if (t < 22) {
        asm volatile("s_waitcnt vmcnt(3)" ::: "memory");  // (t+1)'s loads landed
      } else {
        asm volatile("s_waitcnt vmcnt(0)" ::: "memory");  // last buffer
      }
      __builtin_amdgcn_s_barrier();
    }
    cur = (cur == 2) ? 0 : cur + 1;
    sbuf = (sbuf == 2) ? 0 : sbuf + 1;
  }
#undef STAGE
#undef CO
  // C/D layout (m74/m101): col(n)=lane&31, row(m)=(reg&3)+8*(reg>>2)+4*(lane>>5)
  const int n_out = bj + n0w + (lane & 31);
  float* cp = Ct + (size_t)n_out * 4096 + bm + m0w + 4 * hi32;
#pragma unroll
  for (int r = 0; r < 4; ++r) {
    f32x4 v;
#pragma unroll
    for (int q = 0; q < 4; ++q) v[q] = aa[4 * r + q] + 0.015625f * ab[4 * r + q];
    *(f32x4*)(cp + 8 * r) = v;
  }
}

// ---------------------------------------------------------------------------
// Kernel 3: per-(b,c) tap-combine + prefix-max / suffix-max scans
// ---------------------------------------------------------------------------
__global__ __launch_bounds__(256) void scan_kernel(const float* __restrict__ Ct,
                                                   const int* __restrict__ wsl,
                                                   float* __restrict__ PM2,
                                                   float* __restrict__ SM2) {
  int pair = blockIdx.x * 4 + (threadIdx.x >> 6);
  int b = pair >> 7;
  int c = pair & 127;
  int lane = threadIdx.x & 63;
  int mb = b * 512;
  int t0 = lane * 8;
  const float* p0 = Ct + (size_t)(0 + c) * 4096 + mb;
  const float* p1 = Ct + (size_t)(128 + c) * 4096 + mb;
  const float* p2 = Ct + (size_t)(256 + c) * 4096 + mb;
  float v[8];
#pragma unroll
  for (int i = 0; i < 8; i++) {
    int t = t0 + i;
    v[i] = (t < 494) ? (p0[t] + p1[t + 1] + p2[t + 2]) : NEG_INF;
  }
#pragma unroll
  for (int i = 1; i < 8; i++) v[i] = fmaxf(v[i], v[i - 1]);
  float x = v[7];
#pragma unroll
  for (int d = 1; d < 64; d <<= 1) {
    float y = __shfl_up(x, d);
    if (lane >= d) x = fmaxf(x, y);
  }
  float excl = __shfl_up(x, 1);
  if (lane == 0) excl = NEG_INF;
  float* pm = PM2 + (size_t)pair * 512;
#pragma unroll
  for (int i = 0; i < 8; i++) {
    int t = t0 + i;
    if (t < 494) pm[t] = fmaxf(v[i], excl);
  }
  const float* s0 = Ct + (size_t)(768 + c) * 4096 + mb;
  const float* s1 = Ct + (size_t)(896 + c) * 4096 + mb;
  const float* s2 = Ct + (size_t)(1024 + c) * 4096 + mb;
  int qmax = wsl[b] - 3;
  if (qmax > 509) qmax = 509;
  float u[8];
#pragma unroll
  for (int i = 0; i < 8; i++) {
    int q = t0 + i;
    u[i] = (q <= qmax) ? (s0[q] + s1[q + 1] + s2[q + 2]) : NEG_INF;
  }
#pragma unroll
  for (int i = 6; i >= 0; i--) u[i] = fmaxf(u[i], u[i + 1]);
  float xr = u[0];
#pragma unroll
  for (int d = 1; d < 64; d <<= 1) {
    float y = __shfl_down(xr, d);
    if (lane < 64 - d) xr = fmaxf(xr, y);
  }
  float exclr = __shfl_down(xr, 1);
  if (lane == 63) exclr = NEG_INF;
  float* sm = SM2 + (size_t)pair * 512;
#pragma unroll
  for (int i = 0; i < 8; i++) sm[t0 + i] = fmaxf(u[i], exclr);
}

// ---------------------------------------------------------------------------
// Kernel 4: per-span features + coalesced FC + sigmoid + threshold
// ---------------------------------------------------------------------------
__global__ __launch_bounds__(128) void span_kernel(
    const float* __restrict__ Ct, const float* __restrict__ PM2,
    const float* __restrict__ SM2, const float* __restrict__ prefix_b,
    const float* __restrict__ span_b, const float* __restrict__ suffix_b,
    const float* __restrict__ fcT, const float* __restrict__ fc_b,
    const int* __restrict__ spans, const int* __restrict__ wsl,
    float* __restrict__ out) {
  __shared__ float sfeat[384];
  __shared__ float part[64];
  int sp = blockIdx.x;
  int b = sp >> 5;
  int c = threadIdx.x;
  int s = spans[sp * 2], e = spans[sp * 2 + 1];
  int Lb = wsl[b];
  int mb = b * 512;
  {  // prefix (T=496)
    const float* t0p = Ct + (size_t)c * 4096 + mb;
    const float* t1p = Ct + (size_t)(128 + c) * 4096 + mb;
    float m = NEG_INF;
    if (s >= 3) m = fmaxf(m, PM2[(size_t)(b * 128 + c) * 512 + s - 3]);
    if (s >= 2 && s <= 495) m = fmaxf(m, t0p[s - 2] + t1p[s - 1]);
    if (s >= 1 && s <= 494) m = fmaxf(m, t0p[s - 1]);
    if (s <= 493) m = fmaxf(m, 0.0f);
    sfeat[c] = m + prefix_b[c];
  }
  {  // span (T=16)
    const float* u0 = Ct + (size_t)(384 + c) * 4096 + mb;
    const float* u1 = Ct + (size_t)(512 + c) * 4096 + mb;
    const float* u2 = Ct + (size_t)(640 + c) * 4096 + mb;
    int w = e - s;
    float m = NEG_INF;
    for (int p = 0; p + 2 < w; ++p)
      m = fmaxf(m, u0[s + p] + u1[s + p + 1] + u2[s + p + 2]);
    if (w >= 2 && w <= 15) m = fmaxf(m, u0[s + w - 2] + u1[s + w - 1]);
    if (w <= 14) m = fmaxf(m, u0[s + w - 1]);
    if (w <= 13) m = fmaxf(m, 0.0f);
    sfeat[128 + c] = m + span_b[c];
  }
  {  // suffix (T=511)
    const float* x0 = Ct + (size_t)(768 + c) * 4096 + mb;
    const float* x1 = Ct + (size_t)(896 + c) * 4096 + mb;
    float m = NEG_INF;
    if (e <= Lb - 3) m = fmaxf(m, SM2[(size_t)(b * 128 + c) * 512 + e]);
    if (Lb - 2 - e >= 0 && Lb - 2 - e <= 508)
      m = fmaxf(m, x0[Lb - 2] + x1[Lb - 1]);
    if (Lb - 1 - e >= 0 && Lb - 1 - e <= 508) m = fmaxf(m, x0[Lb - 1]);
    if (Lb - e <= 508) m = fmaxf(m, 0.0f);
    sfeat[256 + c] = m + suffix_b[c];
  }
  __syncthreads();
  {
    int cc = threadIdx.x & 63;
    int half = threadIdx.x >> 6;
    float acc2 = 0.0f;
    const float* fp = fcT + (size_t)(half * 192) * 64 + cc;
    const float* sf = sfeat + half * 192;
#pragma unroll 8
    for (int i = 0; i < 192; ++i) acc2 = fmaf(sf[i], fp[(size_t)i * 64], acc2);
    if (half) part[cc] = acc2;
    __syncthreads();
    if (!half) {
      float a = acc2 + part[cc] + fc_b[cc];
      float pr = 1.0f / (1.0f + expf(-a));
      out[sp * 64 + cc] = pr;
      out[16384 + sp * 64 + cc] = (pr > 0.5f) ? 1.0f : 0.0f;
    }
  }
}

// ---------------------------------------------------------------------------
extern "C" void kernel_launch(void* const* d_in, const int* in_sizes, int n_in,
                              void* d_out, int out_size, void* d_ws,
                              size_t ws_size, hipStream_t stream) {
  const float* tokens = (const float*)d_in[0];
  const float* span_w = (const float*)d_in[1];
  const float* span_b = (const float*)d_in[2];
  const float* prefix_w = (const float*)d_in[3];
  const float* prefix_b = (const float*)d_in[4];
  const float* suffix_w = (const float*)d_in[5];
  const float* suffix_b = (const float*)d_in[6];
  const float* fc_w = (const float*)d_in[7];
  const float* fc_b = (const float*)d_in[8];
  const int* spans = (const int*)d_in[9];
  const int* wsl = (const int*)d_in[10];
  float* out = (float*)d_out;

  char* ws = (char*)d_ws;
  float* Ct = (float*)ws;                     // 1152*4096*4 = 18874368
  _Float16* A2 = (_Float16*)(ws + 18874368);  // 4096*1536*2 = 12582912
  _Float16* Bt = (_Float16*)(ws + 31457280);  // 1152*1536*2 =  3538944
  float* PM2 = (float*)(ws + 34996224);       // 2097152
  float* SM2 = (float*)(ws + 37093376);       // 2097152
  float* fcT = (float*)(ws + 39190528);       // 98304

  hipLaunchKernelGGL(prep, dim3(3312), dim3(256), 0, stream, tokens, span_w,
                     prefix_w, suffix_w, fc_w, A2, Bt, fcT);
  hipLaunchKernelGGL(gemm_f16, dim3(32, 18), dim3(512), 0, stream, A2, Bt, Ct);
  hipLaunchKernelGGL(scan_kernel, dim3(256), dim3(256), 0, stream, Ct, wsl,
                     PM2, SM2);
  hipLaunchKernelGGL(span_kernel, dim3(256), dim3(128), 0, stream, Ct, PM2,
                     SM2, prefix_b, span_b, suffix_b, fcT, fc_b, spans, wsl,
                     out);
}

// Round 3
// 146.818 us; speedup vs baseline: 1.0591x; 1.0591x over previous
//
#include <hip/hip_runtime.h>
#include <hip/hip_bf16.h>
#include <math.h>

// B=8, N=32, S=512, H=768, K=3, C=128, L=64, W=16
#define NEG_INF (-1e30f)

typedef _Float16 half8 __attribute__((ext_vector_type(8)));
typedef _Float16 half4 __attribute__((ext_vector_type(4)));
typedef float f32x4 __attribute__((ext_vector_type(4)));
typedef float f32x16 __attribute__((ext_vector_type(16)));

__device__ __forceinline__ void load_lds16(const void* g, void* l) {
  __builtin_amdgcn_global_load_lds((const __attribute__((address_space(1))) void*)g,
                                   (__attribute__((address_space(3))) void*)l, 16, 0, 0);
}

// ---------------------------------------------------------------------------
// Fragment-major K-layout (NEW this round; kills the measured 4cy/read LDS
// conflict):  k-tap k (0..767) of plane p lives in group g = p*4 + ks*2 + h
// of K-step t, where t=k>>5, ks=(k>>4)&1, h=(k>>3)&1, j=k&7.
//   A2t[((t*8+g)*4096 + m)*8 + j]   (4096 x 1536 halfs, 12.58 MB)
//   Btt[((t*8+g)*1152 + jrow)*8 + j] (1152 x 1536 halfs, 3.54 MB)
// GEMM LDS tile = [g][row][8] contiguous -> frag reads are contiguous 512B
// per half-wave (m134 conflict-free pattern) and glds staging is a linear
// 1KB copy per instruction.
// ---------------------------------------------------------------------------

// ---------------------------------------------------------------------------
// Kernel 1 (prep): hi/lo 2-plane split into fragment-major layout + fcT.
//   blocks 0..255   : A (16 m-rows each, LDS transpose for coalesced IO)
//   blocks 256..399 : B (36864 (ws,h8,c) threads, c-inner for coalesced wr)
//   blocks 400..495 : fcT
// ---------------------------------------------------------------------------
__global__ __launch_bounds__(256) void prep(
    const float* __restrict__ tokens, const float* __restrict__ span_w,
    const float* __restrict__ prefix_w, const float* __restrict__ suffix_w,
    const float* __restrict__ fc_w, _Float16* __restrict__ A2t,
    _Float16* __restrict__ Btt, float* __restrict__ fcT) {
  __shared__ _Float16 lds[16 * 1544];  // [ml][hi768|lo768], row pad 8 halfs
  int bid = blockIdx.x;
  int t = threadIdx.x;
  if (bid < 256) {  // A: rows m0..m0+15
    int m0 = bid * 16;
#pragma unroll
    for (int r = 0; r < 12; ++r) {
      int idx4 = r * 256 + t;  // 3072 float4 = 16x768 floats
      int ml = idx4 / 192;
      int hh = (idx4 % 192) * 4;
      float4 x = *(const float4*)(tokens + (size_t)m0 * 768 + (size_t)idx4 * 4);
      float xs[4] = {x.x, x.y, x.z, x.w};
#pragma unroll
      for (int i = 0; i < 4; ++i) {
        _Float16 h_ = (_Float16)xs[i];
        lds[ml * 1544 + hh + i] = h_;
        lds[ml * 1544 + 768 + hh + i] = (_Float16)((xs[i] - (float)h_) * 64.0f);
      }
    }
    __syncthreads();
#pragma unroll
    for (int rep = 0; rep < 12; ++rep) {
      int tg = rep * 16 + (t >> 4);  // 0..191
      int ml = t & 15;
      int g = tg & 7;
      int tt = tg >> 3;
      int p = g >> 2, ks = (g >> 1) & 1, h2 = g & 1;
      int ksrc = tt * 32 + ks * 16 + h2 * 8;
      half8 v = *(const half8*)&lds[ml * 1544 + p * 768 + ksrc];
      *(half8*)(A2t + ((size_t)tg * 4096 + m0 + ml) * 8) = v;
    }
  } else if (bid < 400) {  // B
    int g = (bid - 256) * 256 + t;  // over 3*96*128 = 36864, c-inner
    int ws = g / 12288;
    int r = g % 12288;
    int h8 = r >> 7, c = r & 127;
    int h0 = h8 * 8;
    const float* wsrc = (ws == 0) ? prefix_w : (ws == 1) ? span_w : suffix_w;
    const float* src = wsrc + ((size_t)c * 768 + h0) * 3;
    float wv[24];
#pragma unroll
    for (int i = 0; i < 6; ++i) *(float4*)&wv[i * 4] = *(const float4*)(src + i * 4);
    int tt = h0 >> 5, ks = (h0 >> 4) & 1, h2 = (h0 >> 3) & 1;
    int g_hi = ks * 2 + h2;
#pragma unroll
    for (int tap = 0; tap < 3; ++tap) {
      half8 hi, lo;
#pragma unroll
      for (int i = 0; i < 8; ++i) {
        float x = wv[i * 3 + tap];
        _Float16 h_ = (_Float16)x;
        hi[i] = h_;
        lo[i] = (_Float16)((x - (float)h_) * 64.0f);
      }
      int j = ws * 384 + tap * 128 + c;
      *(half8*)(Btt + ((size_t)(tt * 8 + g_hi) * 1152 + j) * 8) = hi;
      *(half8*)(Btt + ((size_t)(tt * 8 + g_hi + 4) * 1152 + j) * 8) = lo;
    }
  } else {  // fcT
    int g = (bid - 400) * 256 + t;  // 24576
    int i = g >> 6, c = g & 63;
    fcT[g] = fc_w[c * 384 + i];
  }
}

// ---------------------------------------------------------------------------
// Kernel 2: MFMA GEMM, mfma_f32_32x32x16_f16, fragment-major LDS.
//   Ct[j][m] = aa + 2^-6 * ab;  per k16: aa += A0*B0; ab += A1*B0 + A0*B1.
//   M=4096, N=1152. BM=128, BN=64, BK=32taps(x2 planes), 512 thr (8 waves),
//   wave-tile 32x32, grid (32,18)=576 (2.25 blk/CU, LDS 48KB -> 3 blk/CU).
//   LDS S[buf] = [A: 8g x 128row x 16B | B: 8g x 64row x 16B] = 24KB.
//   Frag read = contiguous 512B per half-wave -> no bank conflicts (was
//   measured +4cy/read with the old row-major XOR layout, r1/r2 counters).
//   Pipeline: depth-2 prefetch, 2 buffers, 2 barriers/iter, vmcnt(3) steady
//   (never 0 mid-loop); stage into cur AFTER barrier1 proves all reads done.
// ---------------------------------------------------------------------------
__global__ __launch_bounds__(512) void gemm_f16(const _Float16* __restrict__ A2t,
                                                const _Float16* __restrict__ Btt,
                                                float* __restrict__ Ct) {
  __shared__ _Float16 S[2][12288];  // 2 x 24KB
  const int bm = blockIdx.x * 128;
  const int bj = blockIdx.y * 64;
  const int tid = threadIdx.x;
  const int w = tid >> 6;
  const int lane = tid & 63;
  // --- staging: 24 linear 1KB units/step; wave w owns units 3w..3w+2.
  //     unit u<16: A group g=u>>1, rows (u&1)*64..+63 -> dst halfs u*512
  //     unit u>=16: B group g=u-16               -> dst halfs u*512
  const int u0 = w * 3;
  const _Float16* su[3];
  size_t ts[3];
  int du[3];
#pragma unroll
  for (int i = 0; i < 3; ++i) {
    int u = u0 + i;
    du[i] = u * 512;
    if (u < 16) {
      su[i] = A2t + (size_t)(u >> 1) * 32768 + ((size_t)bm + (u & 1) * 64 + lane) * 8;
      ts[i] = 262144;  // 8 groups * 4096 * 8 halfs per K-step
    } else {
      su[i] = Btt + (size_t)(u - 16) * 9216 + ((size_t)bj + lane) * 8;
      ts[i] = 73728;  // 8 * 1152 * 8
    }
  }
  const _Float16* su0 = su[0];
  const _Float16* su1 = su[1];
  const _Float16* su2 = su[2];
  const size_t ts0 = ts[0], ts1 = ts[1], ts2 = ts[2];
  const int du0 = du[0], du1 = du[1], du2 = du[2];
#define STAGE(buf, t)                                      \
  do {                                                     \
    load_lds16(su0 + (size_t)(t) * ts0, &S[(buf)][du0]);   \
    load_lds16(su1 + (size_t)(t) * ts1, &S[(buf)][du1]);   \
    load_lds16(su2 + (size_t)(t) * ts2, &S[(buf)][du2]);   \
  } while (0)
  // --- fragment read offsets (halfs): a at g*1024 + ml*8, b at 8192+g*512+jl*8
  const int ln31 = lane & 31;
  const int hi32 = lane >> 5;
  const int m0w = (w & 3) * 32;
  const int n0w = (w >> 2) * 32;
  const int aoff = (m0w + ln31) * 8;
  const int boff = 8192 + (n0w + ln31) * 8;
  f32x16 aa, ab;
#pragma unroll
  for (int q = 0; q < 16; ++q) {
    aa[q] = 0.f;
    ab[q] = 0.f;
  }
  // prologue: stage t=0,1 (6 loads in flight), require only t=0 (oldest 3)
  STAGE(0, 0);
  STAGE(1, 1);
  asm volatile("s_waitcnt vmcnt(3)" ::: "memory");
  asm volatile("s_barrier" ::: "memory");

  for (int t = 0; t < 24; ++t) {
    const int cur = t & 1;
    half8 a0[2], a1[2], b0[2], b1[2];
#pragma unroll
    for (int ks = 0; ks < 2; ++ks) {
      const int gb = ks * 2 + hi32;  // hi-plane group; lo = gb+4
      a0[ks] = *(const half8*)&S[cur][gb * 1024 + aoff];
      a1[ks] = *(const half8*)&S[cur][(gb + 4) * 1024 + aoff];
      b0[ks] = *(const half8*)&S[cur][boff + gb * 512];
      b1[ks] = *(const half8*)&S[cur][boff + (gb + 4) * 512];
    }
    asm volatile("s_waitcnt lgkmcnt(0)" ::: "memory");  // my reads retired
    __builtin_amdgcn_sched_barrier(0);
    asm volatile("s_barrier" ::: "memory");  // ALL waves' reads retired
    if (t + 2 < 24) STAGE(cur, t + 2);       // overwrite cur: now safe
    __builtin_amdgcn_s_setprio(1);
#pragma unroll
    for (int ks = 0; ks < 2; ++ks) {
      aa = __builtin_amdgcn_mfma_f32_32x32x16_f16(a0[ks], b0[ks], aa, 0, 0, 0);
      ab = __builtin_amdgcn_mfma_f32_32x32x16_f16(a1[ks], b0[ks], ab, 0, 0, 0);
      ab = __builtin_amdgcn_mfma_f32_32x32x16_f16(a0[ks], b1[ks], ab, 0, 0, 0);
    }
    __builtin_amdgcn_s_setprio(0);
    if (t < 23) {
      if (t < 22) {
        asm volatile("s_waitcnt vmcnt(3)" ::: "memory");  // t+1's 3 landed
      } else {
        asm volatile("s_waitcnt vmcnt(0)" ::: "memory");  // last buffer
      }
      asm volatile("s_barrier" ::: "memory");
    }
  }
#undef STAGE
  // C/D layout (m74/m101): col(n)=lane&31, row(m)=(reg&3)+8*(reg>>2)+4*(lane>>5)
  const int n_out = bj + n0w + ln31;
  float* cp = Ct + (size_t)n_out * 4096 + bm + m0w + 4 * hi32;
#pragma unroll
  for (int r = 0; r < 4; ++r) {
    f32x4 v;
#pragma unroll
    for (int q = 0; q < 4; ++q) v[q] = aa[4 * r + q] + 0.015625f * ab[4 * r + q];
    *(f32x4*)(cp + 8 * r) = v;
  }
}

// ---------------------------------------------------------------------------
// Kernel 3: per-(b,c) tap-combine + prefix-max / suffix-max scans
// ---------------------------------------------------------------------------
__global__ __launch_bounds__(256) void scan_kernel(const float* __restrict__ Ct,
                                                   const int* __restrict__ wsl,
                                                   float* __restrict__ PM2,
                                                   float* __restrict__ SM2) {
  int pair = blockIdx.x * 4 + (threadIdx.x >> 6);
  int b = pair >> 7;
  int c = pair & 127;
  int lane = threadIdx.x & 63;
  int mb = b * 512;
  int t0 = lane * 8;
  const float* p0 = Ct + (size_t)(0 + c) * 4096 + mb;
  const float* p1 = Ct + (size_t)(128 + c) * 4096 + mb;
  const float* p2 = Ct + (size_t)(256 + c) * 4096 + mb;
  float v[8];
#pragma unroll
  for (int i = 0; i < 8; i++) {
    int t = t0 + i;
    v[i] = (t < 494) ? (p0[t] + p1[t + 1] + p2[t + 2]) : NEG_INF;
  }
#pragma unroll
  for (int i = 1; i < 8; i++) v[i] = fmaxf(v[i], v[i - 1]);
  float x = v[7];
#pragma unroll
  for (int d = 1; d < 64; d <<= 1) {
    float y = __shfl_up(x, d);
    if (lane >= d) x = fmaxf(x, y);
  }
  float excl = __shfl_up(x, 1);
  if (lane == 0) excl = NEG_INF;
  float* pm = PM2 + (size_t)pair * 512;
#pragma unroll
  for (int i = 0; i < 8; i++) {
    int t = t0 + i;
    if (t < 494) pm[t] = fmaxf(v[i], excl);
  }
  const float* s0 = Ct + (size_t)(768 + c) * 4096 + mb;
  const float* s1 = Ct + (size_t)(896 + c) * 4096 + mb;
  const float* s2 = Ct + (size_t)(1024 + c) * 4096 + mb;
  int qmax = wsl[b] - 3;
  if (qmax > 509) qmax = 509;
  float u[8];
#pragma unroll
  for (int i = 0; i < 8; i++) {
    int q = t0 + i;
    u[i] = (q <= qmax) ? (s0[q] + s1[q + 1] + s2[q + 2]) : NEG_INF;
  }
#pragma unroll
  for (int i = 6; i >= 0; i--) u[i] = fmaxf(u[i], u[i + 1]);
  float xr = u[0];
#pragma unroll
  for (int d = 1; d < 64; d <<= 1) {
    float y = __shfl_down(xr, d);
    if (lane < 64 - d) xr = fmaxf(xr, y);
  }
  float exclr = __shfl_down(xr, 1);
  if (lane == 63) exclr = NEG_INF;
  float* sm = SM2 + (size_t)pair * 512;
#pragma unroll
  for (int i = 0; i < 8; i++) sm[t0 + i] = fmaxf(u[i], exclr);
}

// ---------------------------------------------------------------------------
// Kernel 4: per-span features + coalesced FC + sigmoid + threshold
// ---------------------------------------------------------------------------
__global__ __launch_bounds__(128) void span_kernel(
    const float* __restrict__ Ct, const float* __restrict__ PM2,
    const float* __restrict__ SM2, const float* __restrict__ prefix_b,
    const float* __restrict__ span_b, const float* __restrict__ suffix_b,
    const float* __restrict__ fcT, const float* __restrict__ fc_b,
    const int* __restrict__ spans, const int* __restrict__ wsl,
    float* __restrict__ out) {
  __shared__ float sfeat[384];
  __shared__ float part[64];
  int sp = blockIdx.x;
  int b = sp >> 5;
  int c = threadIdx.x;
  int s = spans[sp * 2], e = spans[sp * 2 + 1];
  int Lb = wsl[b];
  int mb = b * 512;
  {  // prefix (T=496)
    const float* t0p = Ct + (size_t)c * 4096 + mb;
    const float* t1p = Ct + (size_t)(128 + c) * 4096 + mb;
    float m = NEG_INF;
    if (s >= 3) m = fmaxf(m, PM2[(size_t)(b * 128 + c) * 512 + s - 3]);
    if (s >= 2 && s <= 495) m = fmaxf(m, t0p[s - 2] + t1p[s - 1]);
    if (s >= 1 && s <= 494) m = fmaxf(m, t0p[s - 1]);
    if (s <= 493) m = fmaxf(m, 0.0f);
    sfeat[c] = m + prefix_b[c];
  }
  {  // span (T=16)
    const float* u0 = Ct + (size_t)(384 + c) * 4096 + mb;
    const float* u1 = Ct + (size_t)(512 + c) * 4096 + mb;
    const float* u2 = Ct + (size_t)(640 + c) * 4096 + mb;
    int w = e - s;
    float m = NEG_INF;
    for (int p = 0; p + 2 < w; ++p)
      m = fmaxf(m, u0[s + p] + u1[s + p + 1] + u2[s + p + 2]);
    if (w >= 2 && w <= 15) m = fmaxf(m, u0[s + w - 2] + u1[s + w - 1]);
    if (w <= 14) m = fmaxf(m, u0[s + w - 1]);
    if (w <= 13) m = fmaxf(m, 0.0f);
    sfeat[128 + c] = m + span_b[c];
  }
  {  // suffix (T=511)
    const float* x0 = Ct + (size_t)(768 + c) * 4096 + mb;
    const float* x1 = Ct + (size_t)(896 + c) * 4096 + mb;
    float m = NEG_INF;
    if (e <= Lb - 3) m = fmaxf(m, SM2[(size_t)(b * 128 + c) * 512 + e]);
    if (Lb - 2 - e >= 0 && Lb - 2 - e <= 508)
      m = fmaxf(m, x0[Lb - 2] + x1[Lb - 1]);
    if (Lb - 1 - e >= 0 && Lb - 1 - e <= 508) m = fmaxf(m, x0[Lb - 1]);
    if (Lb - e <= 508) m = fmaxf(m, 0.0f);
    sfeat[256 + c] = m + suffix_b[c];
  }
  __syncthreads();
  {
    int cc = threadIdx.x & 63;
    int half = threadIdx.x >> 6;
    float acc2 = 0.0f;
    const float* fp = fcT + (size_t)(half * 192) * 64 + cc;
    const float* sf = sfeat + half * 192;
#pragma unroll 8
    for (int i = 0; i < 192; ++i) acc2 = fmaf(sf[i], fp[(size_t)i * 64], acc2);
    if (half) part[cc] = acc2;
    __syncthreads();
    if (!half) {
      float a = acc2 + part[cc] + fc_b[cc];
      float pr = 1.0f / (1.0f + expf(-a));
      out[sp * 64 + cc] = pr;
      out[16384 + sp * 64 + cc] = (pr > 0.5f) ? 1.0f : 0.0f;
    }
  }
}

// ---------------------------------------------------------------------------
extern "C" void kernel_launch(void* const* d_in, const int* in_sizes, int n_in,
                              void* d_out, int out_size, void* d_ws,
                              size_t ws_size, hipStream_t stream) {
  const float* tokens = (const float*)d_in[0];
  const float* span_w = (const float*)d_in[1];
  const float* span_b = (const float*)d_in[2];
  const float* prefix_w = (const float*)d_in[3];
  const float* prefix_b = (const float*)d_in[4];
  const float* suffix_w = (const float*)d_in[5];
  const float* suffix_b = (const float*)d_in[6];
  const float* fc_w = (const float*)d_in[7];
  const float* fc_b = (const float*)d_in[8];
  const int* spans = (const int*)d_in[9];
  const int* wsl = (const int*)d_in[10];
  float* out = (float*)d_out;

  char* ws = (char*)d_ws;
  float* Ct = (float*)ws;                      // 1152*4096*4 = 18874368
  _Float16* A2t = (_Float16*)(ws + 18874368);  // 4096*1536*2 = 12582912
  _Float16* Btt = (_Float16*)(ws + 31457280);  // 1152*1536*2 =  3538944
  float* PM2 = (float*)(ws + 34996224);        // 2097152
  float* SM2 = (float*)(ws + 37093376);        // 2097152
  float* fcT = (float*)(ws + 39190528);        // 98304

  hipLaunchKernelGGL(prep, dim3(496), dim3(256), 0, stream, tokens, span_w,
                     prefix_w, suffix_w, fc_w, A2t, Btt, fcT);
  hipLaunchKernelGGL(gemm_f16, dim3(32, 18), dim3(512), 0, stream, A2t, Btt, Ct);
  hipLaunchKernelGGL(scan_kernel, dim3(256), dim3(256), 0, stream, Ct, wsl,
                     PM2, SM2);
  hipLaunchKernelGGL(span_kernel, dim3(256), dim3(128), 0, stream, Ct, PM2,
                     SM2, prefix_b, span_b, suffix_b, fcT, fc_b, spans, wsl,
                     out);
}

// Round 4
// 143.197 us; speedup vs baseline: 1.0859x; 1.0253x over previous
//
#include <hip/hip_runtime.h>
#include <hip/hip_bf16.h>
#include <math.h>

// B=8, N=32, S=512, H=768, K=3, C=128, L=64, W=16
#define NEG_INF (-1e30f)

typedef _Float16 half8 __attribute__((ext_vector_type(8)));
typedef _Float16 half4 __attribute__((ext_vector_type(4)));
typedef float f32x4 __attribute__((ext_vector_type(4)));
typedef float f32x16 __attribute__((ext_vector_type(16)));

__device__ __forceinline__ void load_lds16(const void* g, void* l) {
  __builtin_amdgcn_global_load_lds((const __attribute__((address_space(1))) void*)g,
                                   (__attribute__((address_space(3))) void*)l, 16, 0, 0);
}

// ---------------------------------------------------------------------------
// Fragment-major K-layout (r3, kept — killed the measured 4cy/read conflict):
//   k-tap k (0..767) of plane p lives in group g = p*4 + ks*2 + h of K-step t,
//   where t=k>>5, ks=(k>>4)&1, h=(k>>3)&1, j=k&7.
//   A2t[((t*8+g)*4096 + m)*8 + j]    (4096 x 1536 halfs)
//   Btt[((t*8+g)*1152 + jrow)*8 + j] (1152 x 1536 halfs)
// ---------------------------------------------------------------------------

// ---------------------------------------------------------------------------
// Kernel 1 (prep): hi/lo 2-plane split into fragment-major layout + fcT.
// ---------------------------------------------------------------------------
__global__ __launch_bounds__(256) void prep(
    const float* __restrict__ tokens, const float* __restrict__ span_w,
    const float* __restrict__ prefix_w, const float* __restrict__ suffix_w,
    const float* __restrict__ fc_w, _Float16* __restrict__ A2t,
    _Float16* __restrict__ Btt, float* __restrict__ fcT) {
  __shared__ _Float16 lds[16 * 1544];  // [ml][hi768|lo768], row pad 8 halfs
  int bid = blockIdx.x;
  int t = threadIdx.x;
  if (bid < 256) {  // A: rows m0..m0+15
    int m0 = bid * 16;
#pragma unroll
    for (int r = 0; r < 12; ++r) {
      int idx4 = r * 256 + t;  // 3072 float4 = 16x768 floats
      int ml = idx4 / 192;
      int hh = (idx4 % 192) * 4;
      float4 x = *(const float4*)(tokens + (size_t)m0 * 768 + (size_t)idx4 * 4);
      float xs[4] = {x.x, x.y, x.z, x.w};
#pragma unroll
      for (int i = 0; i < 4; ++i) {
        _Float16 h_ = (_Float16)xs[i];
        lds[ml * 1544 + hh + i] = h_;
        lds[ml * 1544 + 768 + hh + i] = (_Float16)((xs[i] - (float)h_) * 64.0f);
      }
    }
    __syncthreads();
#pragma unroll
    for (int rep = 0; rep < 12; ++rep) {
      int tg = rep * 16 + (t >> 4);  // 0..191
      int ml = t & 15;
      int g = tg & 7;
      int tt = tg >> 3;
      int p = g >> 2, ks = (g >> 1) & 1, h2 = g & 1;
      int ksrc = tt * 32 + ks * 16 + h2 * 8;
      half8 v = *(const half8*)&lds[ml * 1544 + p * 768 + ksrc];
      *(half8*)(A2t + ((size_t)tg * 4096 + m0 + ml) * 8) = v;
    }
  } else if (bid < 400) {  // B
    int g = (bid - 256) * 256 + t;  // over 3*96*128 = 36864, c-inner
    int ws = g / 12288;
    int r = g % 12288;
    int h8 = r >> 7, c = r & 127;
    int h0 = h8 * 8;
    const float* wsrc = (ws == 0) ? prefix_w : (ws == 1) ? span_w : suffix_w;
    const float* src = wsrc + ((size_t)c * 768 + h0) * 3;
    float wv[24];
#pragma unroll
    for (int i = 0; i < 6; ++i) *(float4*)&wv[i * 4] = *(const float4*)(src + i * 4);
    int tt = h0 >> 5, ks = (h0 >> 4) & 1, h2 = (h0 >> 3) & 1;
    int g_hi = ks * 2 + h2;
#pragma unroll
    for (int tap = 0; tap < 3; ++tap) {
      half8 hi, lo;
#pragma unroll
      for (int i = 0; i < 8; ++i) {
        float x = wv[i * 3 + tap];
        _Float16 h_ = (_Float16)x;
        hi[i] = h_;
        lo[i] = (_Float16)((x - (float)h_) * 64.0f);
      }
      int j = ws * 384 + tap * 128 + c;
      *(half8*)(Btt + ((size_t)(tt * 8 + g_hi) * 1152 + j) * 8) = hi;
      *(half8*)(Btt + ((size_t)(tt * 8 + g_hi + 4) * 1152 + j) * 8) = lo;
    }
  } else {  // fcT
    int g = (bid - 400) * 256 + t;  // 24576
    int i = g >> 6, c = g & 63;
    fcT[g] = fc_w[c * 384 + i];
  }
}

// ---------------------------------------------------------------------------
// Kernel 2: MFMA GEMM, mfma_f32_32x32x16_f16, fragment-major LDS.
//   Ct[j][m] = aa + 2^-6 * ab;  per k16: aa += A0*B0; ab += A1*B0 + A0*B1.
//   NEW (this round): BM=64, BN=96, grid (64,12)=768 = exactly 3 blocks/CU
//   (was 576 = 2.25/CU -> 33% tail: 64 CUs ran 3 blocks while 192 idled.
//   r0-r3 all sat at 40-48us because makespan = 3*T_block regardless of
//   schedule). 6 waves (384 thr), wave-tile 32x32 (2m x 3n).
//   LDS S[buf] = [A: 8g x 64row x 16B | B: 8g x 96row x 16B] = 20KB, 2 bufs
//   = 40KB -> 3 blocks/CU resident (120KB), 18 waves/CU.
//   Staging: 20 linear 1KB glds units/step; waves 0-1: 4 units, 2-5: 3.
//   Pipeline (r3, kept): depth-2 prefetch, 2 buffers, 2 barriers/iter,
//   counted vmcnt (never 0 mid-loop); stage into cur AFTER barrier1.
// ---------------------------------------------------------------------------
__global__ __launch_bounds__(384) void gemm_f16(const _Float16* __restrict__ A2t,
                                                const _Float16* __restrict__ Btt,
                                                float* __restrict__ Ct) {
  __shared__ _Float16 S[2][10240];  // 2 x 20KB
  const int bm = blockIdx.x * 64;
  const int bj = blockIdx.y * 96;
  const int tid = threadIdx.x;
  const int w = tid >> 6;  // 0..5
  const int lane = tid & 63;
  // --- staging units: u<8: A group u (64 rows, contiguous 1KB);
  //     u>=8: B flat rows (u-8)*64..+63 over [g][96] (per-lane src addr).
  //     dst byte base = u*1024 (A region then B region, both [g][rows][16B]).
  const int nu = (w < 2) ? 4 : 3;
  const int ub = (w < 2) ? (w * 4) : (8 + 3 * (w - 2));
  const _Float16* su[4];
  size_t ts[4];
  int du[4];
#pragma unroll
  for (int i = 0; i < 4; ++i) {
    int u = ub + ((i < nu) ? i : 0);  // dup unit 0 slot for w>=2 (never issued)
    du[i] = u * 512;                  // halfs
    if (u < 8) {
      su[i] = A2t + ((size_t)u * 4096 + bm + lane) * 8;
      ts[i] = 262144;  // 8 groups * 4096 rows * 8 halfs per K-step
    } else {
      int fr = (u - 8) * 64 + lane;  // 0..767
      int g = fr / 96, jr = fr % 96;
      su[i] = Btt + ((size_t)g * 1152 + bj + jr) * 8;
      ts[i] = 73728;  // 8 * 1152 * 8
    }
  }
  const _Float16* su0 = su[0];
  const _Float16* su1 = su[1];
  const _Float16* su2 = su[2];
  const _Float16* su3 = su[3];
  const size_t ts0 = ts[0], ts1 = ts[1], ts2 = ts[2], ts3 = ts[3];
  const int du0 = du[0], du1 = du[1], du2 = du[2], du3 = du[3];
#define STAGE(buf, t)                                              \
  do {                                                             \
    load_lds16(su0 + (size_t)(t) * ts0, &S[(buf)][du0]);           \
    load_lds16(su1 + (size_t)(t) * ts1, &S[(buf)][du1]);           \
    load_lds16(su2 + (size_t)(t) * ts2, &S[(buf)][du2]);           \
    if (w < 2) load_lds16(su3 + (size_t)(t) * ts3, &S[(buf)][du3]); \
  } while (0)
#define WAIT_NU()                                                  \
  do {                                                             \
    if (w < 2)                                                     \
      asm volatile("s_waitcnt vmcnt(4)" ::: "memory");             \
    else                                                           \
      asm volatile("s_waitcnt vmcnt(3)" ::: "memory");             \
  } while (0)
  // --- fragment read offsets (halfs): A at g*512 + (wm*32+ln31)*8;
  //     B at 4096 + g*768 + (wn*32+ln31)*8.
  const int ln31 = lane & 31;
  const int hi32 = lane >> 5;
  const int wm = w & 1;
  const int wn = w >> 1;  // 0..2
  const int aoff = (wm * 32 + ln31) * 8;
  const int boff = 4096 + (wn * 32 + ln31) * 8;
  f32x16 aa, ab;
#pragma unroll
  for (int q = 0; q < 16; ++q) {
    aa[q] = 0.f;
    ab[q] = 0.f;
  }
  // prologue: stage t=0,1 (2*nu in flight), require only t=0 (oldest nu)
  STAGE(0, 0);
  STAGE(1, 1);
  WAIT_NU();
  asm volatile("s_barrier" ::: "memory");

  for (int t = 0; t < 24; ++t) {
    const int cur = t & 1;
    half8 a0[2], a1[2], b0[2], b1[2];
#pragma unroll
    for (int ks = 0; ks < 2; ++ks) {
      const int gb = ks * 2 + hi32;  // hi-plane group; lo = gb+4
      a0[ks] = *(const half8*)&S[cur][gb * 512 + aoff];
      a1[ks] = *(const half8*)&S[cur][(gb + 4) * 512 + aoff];
      b0[ks] = *(const half8*)&S[cur][boff + gb * 768];
      b1[ks] = *(const half8*)&S[cur][boff + (gb + 4) * 768];
    }
    asm volatile("s_waitcnt lgkmcnt(0)" ::: "memory");  // my reads retired
    __builtin_amdgcn_sched_barrier(0);
    asm volatile("s_barrier" ::: "memory");  // ALL waves' reads retired
    if (t + 2 < 24) STAGE(cur, t + 2);       // overwrite cur: now safe
    __builtin_amdgcn_s_setprio(1);
#pragma unroll
    for (int ks = 0; ks < 2; ++ks) {
      aa = __builtin_amdgcn_mfma_f32_32x32x16_f16(a0[ks], b0[ks], aa, 0, 0, 0);
      ab = __builtin_amdgcn_mfma_f32_32x32x16_f16(a1[ks], b0[ks], ab, 0, 0, 0);
      ab = __builtin_amdgcn_mfma_f32_32x32x16_f16(a0[ks], b1[ks], ab, 0, 0, 0);
    }
    __builtin_amdgcn_s_setprio(0);
    if (t < 23) {
      if (t < 22) {
        WAIT_NU();  // t+1's loads landed; t+2's stay in flight
      } else {
        asm volatile("s_waitcnt vmcnt(0)" ::: "memory");  // last buffer
      }
      asm volatile("s_barrier" ::: "memory");
    }
  }
#undef STAGE
#undef WAIT_NU
  // C/D layout (m74/m101): col(n)=lane&31, row(m)=(reg&3)+8*(reg>>2)+4*(lane>>5)
  const int n_out = bj + wn * 32 + ln31;
  float* cp = Ct + (size_t)n_out * 4096 + bm + wm * 32 + 4 * hi32;
#pragma unroll
  for (int r = 0; r < 4; ++r) {
    f32x4 v;
#pragma unroll
    for (int q = 0; q < 4; ++q) v[q] = aa[4 * r + q] + 0.015625f * ab[4 * r + q];
    *(f32x4*)(cp + 8 * r) = v;
  }
}

// ---------------------------------------------------------------------------
// Kernel 3: per-(b,c) tap-combine + prefix-max / suffix-max scans
// ---------------------------------------------------------------------------
__global__ __launch_bounds__(256) void scan_kernel(const float* __restrict__ Ct,
                                                   const int* __restrict__ wsl,
                                                   float* __restrict__ PM2,
                                                   float* __restrict__ SM2) {
  int pair = blockIdx.x * 4 + (threadIdx.x >> 6);
  int b = pair >> 7;
  int c = pair & 127;
  int lane = threadIdx.x & 63;
  int mb = b * 512;
  int t0 = lane * 8;
  const float* p0 = Ct + (size_t)(0 + c) * 4096 + mb;
  const float* p1 = Ct + (size_t)(128 + c) * 4096 + mb;
  const float* p2 = Ct + (size_t)(256 + c) * 4096 + mb;
  float v[8];
#pragma unroll
  for (int i = 0; i < 8; i++) {
    int t = t0 + i;
    v[i] = (t < 494) ? (p0[t] + p1[t + 1] + p2[t + 2]) : NEG_INF;
  }
#pragma unroll
  for (int i = 1; i < 8; i++) v[i] = fmaxf(v[i], v[i - 1]);
  float x = v[7];
#pragma unroll
  for (int d = 1; d < 64; d <<= 1) {
    float y = __shfl_up(x, d);
    if (lane >= d) x = fmaxf(x, y);
  }
  float excl = __shfl_up(x, 1);
  if (lane == 0) excl = NEG_INF;
  float* pm = PM2 + (size_t)pair * 512;
#pragma unroll
  for (int i = 0; i < 8; i++) {
    int t = t0 + i;
    if (t < 494) pm[t] = fmaxf(v[i], excl);
  }
  const float* s0 = Ct + (size_t)(768 + c) * 4096 + mb;
  const float* s1 = Ct + (size_t)(896 + c) * 4096 + mb;
  const float* s2 = Ct + (size_t)(1024 + c) * 4096 + mb;
  int qmax = wsl[b] - 3;
  if (qmax > 509) qmax = 509;
  float u[8];
#pragma unroll
  for (int i = 0; i < 8; i++) {
    int q = t0 + i;
    u[i] = (q <= qmax) ? (s0[q] + s1[q + 1] + s2[q + 2]) : NEG_INF;
  }
#pragma unroll
  for (int i = 6; i >= 0; i--) u[i] = fmaxf(u[i], u[i + 1]);
  float xr = u[0];
#pragma unroll
  for (int d = 1; d < 64; d <<= 1) {
    float y = __shfl_down(xr, d);
    if (lane < 64 - d) xr = fmaxf(xr, y);
  }
  float exclr = __shfl_down(xr, 1);
  if (lane == 63) exclr = NEG_INF;
  float* sm = SM2 + (size_t)pair * 512;
#pragma unroll
  for (int i = 0; i < 8; i++) sm[t0 + i] = fmaxf(u[i], exclr);
}

// ---------------------------------------------------------------------------
// Kernel 4: per-span features + coalesced FC + sigmoid + threshold
// ---------------------------------------------------------------------------
__global__ __launch_bounds__(128) void span_kernel(
    const float* __restrict__ Ct, const float* __restrict__ PM2,
    const float* __restrict__ SM2, const float* __restrict__ prefix_b,
    const float* __restrict__ span_b, const float* __restrict__ suffix_b,
    const float* __restrict__ fcT, const float* __restrict__ fc_b,
    const int* __restrict__ spans, const int* __restrict__ wsl,
    float* __restrict__ out) {
  __shared__ float sfeat[384];
  __shared__ float part[64];
  int sp = blockIdx.x;
  int b = sp >> 5;
  int c = threadIdx.x;
  int s = spans[sp * 2], e = spans[sp * 2 + 1];
  int Lb = wsl[b];
  int mb = b * 512;
  {  // prefix (T=496)
    const float* t0p = Ct + (size_t)c * 4096 + mb;
    const float* t1p = Ct + (size_t)(128 + c) * 4096 + mb;
    float m = NEG_INF;
    if (s >= 3) m = fmaxf(m, PM2[(size_t)(b * 128 + c) * 512 + s - 3]);
    if (s >= 2 && s <= 495) m = fmaxf(m, t0p[s - 2] + t1p[s - 1]);
    if (s >= 1 && s <= 494) m = fmaxf(m, t0p[s - 1]);
    if (s <= 493) m = fmaxf(m, 0.0f);
    sfeat[c] = m + prefix_b[c];
  }
  {  // span (T=16)
    const float* u0 = Ct + (size_t)(384 + c) * 4096 + mb;
    const float* u1 = Ct + (size_t)(512 + c) * 4096 + mb;
    const float* u2 = Ct + (size_t)(640 + c) * 4096 + mb;
    int w = e - s;
    float m = NEG_INF;
    for (int p = 0; p + 2 < w; ++p)
      m = fmaxf(m, u0[s + p] + u1[s + p + 1] + u2[s + p + 2]);
    if (w >= 2 && w <= 15) m = fmaxf(m, u0[s + w - 2] + u1[s + w - 1]);
    if (w <= 14) m = fmaxf(m, u0[s + w - 1]);
    if (w <= 13) m = fmaxf(m, 0.0f);
    sfeat[128 + c] = m + span_b[c];
  }
  {  // suffix (T=511)
    const float* x0 = Ct + (size_t)(768 + c) * 4096 + mb;
    const float* x1 = Ct + (size_t)(896 + c) * 4096 + mb;
    float m = NEG_INF;
    if (e <= Lb - 3) m = fmaxf(m, SM2[(size_t)(b * 128 + c) * 512 + e]);
    if (Lb - 2 - e >= 0 && Lb - 2 - e <= 508)
      m = fmaxf(m, x0[Lb - 2] + x1[Lb - 1]);
    if (Lb - 1 - e >= 0 && Lb - 1 - e <= 508) m = fmaxf(m, x0[Lb - 1]);
    if (Lb - e <= 508) m = fmaxf(m, 0.0f);
    sfeat[256 + c] = m + suffix_b[c];
  }
  __syncthreads();
  {
    int cc = threadIdx.x & 63;
    int half = threadIdx.x >> 6;
    float acc2 = 0.0f;
    const float* fp = fcT + (size_t)(half * 192) * 64 + cc;
    const float* sf = sfeat + half * 192;
#pragma unroll 8
    for (int i = 0; i < 192; ++i) acc2 = fmaf(sf[i], fp[(size_t)i * 64], acc2);
    if (half) part[cc] = acc2;
    __syncthreads();
    if (!half) {
      float a = acc2 + part[cc] + fc_b[cc];
      float pr = 1.0f / (1.0f + expf(-a));
      out[sp * 64 + cc] = pr;
      out[16384 + sp * 64 + cc] = (pr > 0.5f) ? 1.0f : 0.0f;
    }
  }
}

// ---------------------------------------------------------------------------
extern "C" void kernel_launch(void* const* d_in, const int* in_sizes, int n_in,
                              void* d_out, int out_size, void* d_ws,
                              size_t ws_size, hipStream_t stream) {
  const float* tokens = (const float*)d_in[0];
  const float* span_w = (const float*)d_in[1];
  const float* span_b = (const float*)d_in[2];
  const float* prefix_w = (const float*)d_in[3];
  const float* prefix_b = (const float*)d_in[4];
  const float* suffix_w = (const float*)d_in[5];
  const float* suffix_b = (const float*)d_in[6];
  const float* fc_w = (const float*)d_in[7];
  const float* fc_b = (const float*)d_in[8];
  const int* spans = (const int*)d_in[9];
  const int* wsl = (const int*)d_in[10];
  float* out = (float*)d_out;

  char* ws = (char*)d_ws;
  float* Ct = (float*)ws;                      // 1152*4096*4 = 18874368
  _Float16* A2t = (_Float16*)(ws + 18874368);  // 4096*1536*2 = 12582912
  _Float16* Btt = (_Float16*)(ws + 31457280);  // 1152*1536*2 =  3538944
  float* PM2 = (float*)(ws + 34996224);        // 2097152
  float* SM2 = (float*)(ws + 37093376);        // 2097152
  float* fcT = (float*)(ws + 39190528);        // 98304

  hipLaunchKernelGGL(prep, dim3(496), dim3(256), 0, stream, tokens, span_w,
                     prefix_w, suffix_w, fc_w, A2t, Btt, fcT);
  hipLaunchKernelGGL(gemm_f16, dim3(64, 12), dim3(384), 0, stream, A2t, Btt, Ct);
  hipLaunchKernelGGL(scan_kernel, dim3(256), dim3(256), 0, stream, Ct, wsl,
                     PM2, SM2);
  hipLaunchKernelGGL(span_kernel, dim3(256), dim3(128), 0, stream, Ct, PM2,
                     SM2, prefix_b, span_b, suffix_b, fcT, fc_b, spans, wsl,
                     out);
}